// Round 7
// baseline (833.520 us; speedup 1.0000x reference)
//
#include <hip/hip_runtime.h>
#include <hip/hip_bf16.h>

#define H2C 256   // 2*hidden
#define HDC 128   // hidden
#define GATEC 64
#define NBUCK 8
#define NCHUNK 256

typedef unsigned short ushort_t;
typedef unsigned long long ull_t;
typedef __attribute__((ext_vector_type(8))) __bf16 bf16x8;
typedef __attribute__((ext_vector_type(4))) float f32x4;

__device__ inline float bf2f(unsigned short v) {
    union { unsigned u; float f; } t; t.u = ((unsigned)v) << 16; return t.f;
}
__device__ inline unsigned short f2bf(float v) {
    __hip_bfloat16 b = __float2bfloat16(v);
    return *reinterpret_cast<unsigned short*>(&b);
}

__device__ inline void gload_lds16(const void* g, void* l) {
    __builtin_amdgcn_global_load_lds(
        (const __attribute__((address_space(1))) unsigned int*)g,
        (__attribute__((address_space(3))) unsigned int*)l, 16, 0, 0);
}

// ---------------- bf16 MFMA GEMM: C = A @ BT^T. C written slice-major if SLICEMAJ ----------------
// slice-major: C[((col>>5)*M + row)*32 + (col&31)]  (32-feature slices, gather-friendly)
template <bool SLICEMAJ>
__global__ __launch_bounds__(256)
void gemm_bf16_mfma(const ushort_t* __restrict__ A, const ushort_t* __restrict__ BT,
                    ushort_t* __restrict__ C, int M, int Nn, int K)
{
    __shared__ ushort_t Alds[128 * 64];
    __shared__ ushort_t Blds[128 * 64];
    const int tid  = threadIdx.x;
    const int w    = tid >> 6;
    const int lane = tid & 63;
    const int wr   = w >> 1;
    const int wc   = w & 1;
    const int bm   = blockIdx.y * 128;
    const int bn   = blockIdx.x * 128;

    f32x4 acc[4][4] = {};

    for (int k0 = 0; k0 < K; k0 += 64) {
        #pragma unroll
        for (int i = 0; i < 4; ++i) {
            const int lin = i * 256 + tid;
            const int r = lin >> 3, p = lin & 7;
            int rm = bm + r; if (rm >= M) rm = M - 1;
            const ushort_t* ga = A + (size_t)rm * K + k0 + ((p ^ (r & 7)) << 3);
            gload_lds16(ga, &Alds[i * 2048 + w * 512]);
        }
        #pragma unroll
        for (int i = 0; i < 4; ++i) {
            const int lin = i * 256 + tid;
            const int r = lin >> 3, p = lin & 7;
            const ushort_t* gb = BT + (size_t)(bn + r) * K + k0 + ((p ^ (r & 7)) << 3);
            gload_lds16(gb, &Blds[i * 2048 + w * 512]);
        }
        __syncthreads();
        #pragma unroll
        for (int kk = 0; kk < 2; ++kk) {
            bf16x8 af[4], bfr[4];
            #pragma unroll
            for (int m = 0; m < 4; ++m) {
                const int r = wr * 64 + m * 16 + (lane & 15);
                const int s = kk * 4 + (lane >> 4);
                af[m] = *reinterpret_cast<const bf16x8*>(&Alds[r * 64 + ((s ^ (r & 7)) << 3)]);
            }
            #pragma unroll
            for (int n = 0; n < 4; ++n) {
                const int r = wc * 64 + n * 16 + (lane & 15);
                const int s = kk * 4 + (lane >> 4);
                bfr[n] = *reinterpret_cast<const bf16x8*>(&Blds[r * 64 + ((s ^ (r & 7)) << 3)]);
            }
            #pragma unroll
            for (int m = 0; m < 4; ++m)
                #pragma unroll
                for (int n = 0; n < 4; ++n)
                    acc[m][n] = __builtin_amdgcn_mfma_f32_16x16x32_bf16(
                        af[m], bfr[n], acc[m][n], 0, 0, 0);
        }
        __syncthreads();
    }

    #pragma unroll
    for (int m = 0; m < 4; ++m) {
        const int row0 = bm + wr * 64 + m * 16 + ((lane >> 4) << 2);
        #pragma unroll
        for (int n = 0; n < 4; ++n) {
            const int col = bn + wc * 64 + n * 16 + (lane & 15);
            #pragma unroll
            for (int q = 0; q < 4; ++q) {
                const int row = row0 + q;
                if (row < M) {
                    if constexpr (SLICEMAJ)
                        C[((size_t)(col >> 5) * M + row) * 32 + (col & 31)] = f2bf(acc[m][n][q]);
                    else
                        C[(size_t)row * Nn + col] = f2bf(acc[m][n][q]);
                }
            }
        }
    }
}

// ---------------- fp32 -> bf16 convert, two sources into one buffer ----------------
__global__ __launch_bounds__(256)
void f2bf_pair_kernel(const float* __restrict__ in1, const float* __restrict__ in2,
                      ushort_t* __restrict__ out, long long n4each)
{
    long long i = (long long)blockIdx.x * blockDim.x + threadIdx.x;
    const long long stride = (long long)gridDim.x * blockDim.x;
    for (; i < 2 * n4each; i += stride) {
        const float* src = (i < n4each) ? in1 : in2;
        const long long k = (i < n4each) ? i : i - n4each;
        const float4 v = reinterpret_cast<const float4*>(src)[k];
        ushort4 o;
        o.x = f2bf(v.x); o.y = f2bf(v.y); o.z = f2bf(v.z); o.w = f2bf(v.w);
        reinterpret_cast<ushort4*>(out)[i] = o;
    }
}

// ---------------- W[R,C] -> bf16 WT[C,R] ----------------
__global__ __launch_bounds__(256)
void transpose_f2bf_kernel(const float* __restrict__ W, ushort_t* __restrict__ WT, int R, int Ccols)
{
    const int i = blockIdx.x * blockDim.x + threadIdx.x;
    if (i >= R * Ccols) return;
    const int c = i / R, r = i % R;
    WT[(size_t)c * R + r] = f2bf(W[(size_t)r * Ccols + c]);
}

// ---------------- fused CSR build over 3 adjacencies (concatenated virtual rows) ----------------
__global__ __launch_bounds__(256)
void hist3_kernel(const int* __restrict__ r0, const int* __restrict__ r1,
                  const int* __restrict__ rD, int E, int ED, int N, int* __restrict__ cnt)
{
    const long long i = (long long)blockIdx.x * blockDim.x + threadIdx.x;
    const long long tot = 2LL * E + ED;
    if (i >= tot) return;
    int idx;
    if (i < E)            idx = r0[i];
    else if (i < 2LL * E) idx = N + r1[i - E];
    else                  idx = 2 * N + rD[i - 2LL * E];
    atomicAdd(&cnt[idx], 1);
}

__global__ __launch_bounds__(256)
void block_sum_kernel(const int* __restrict__ cnt, int n, int* __restrict__ bsum)
{
    __shared__ int s[256];
    const int tid = threadIdx.x;
    const int i = blockIdx.x * 256 + tid;
    s[tid] = (i < n) ? cnt[i] : 0;
    __syncthreads();
    for (int o = 128; o > 0; o >>= 1) {
        if (tid < o) s[tid] += s[tid + o];
        __syncthreads();
    }
    if (tid == 0) bsum[blockIdx.x] = s[0];
}

__global__ void scan_bsum_kernel(int* __restrict__ bsum, int nb)
{
    if (threadIdx.x == 0) {
        int acc = 0;
        for (int b = 0; b < nb; ++b) { int t = bsum[b]; bsum[b] = acc; acc += t; }
    }
}

__global__ __launch_bounds__(256)
void block_scan_kernel(const int* __restrict__ cnt, int n, const int* __restrict__ bsum,
                       int* __restrict__ g, int tot)
{
    __shared__ int sh[256];
    const int tid = threadIdx.x;
    const int i = blockIdx.x * 256 + tid;
    const int v = (i < n) ? cnt[i] : 0;
    sh[tid] = v;
    __syncthreads();
    for (int o = 1; o < 256; o <<= 1) {
        int t = 0;
        if (tid >= o) t = sh[tid - o];
        __syncthreads();
        sh[tid] += t;
        __syncthreads();
    }
    if (i < n) g[i] = bsum[blockIdx.x] + sh[tid] - v;  // exclusive
    if (i == 0) g[n] = tot;
}

__global__ __launch_bounds__(256)
void copy_int_kernel(const int* __restrict__ src, int* __restrict__ dst, int n)
{
    const int i = blockIdx.x * 256 + threadIdx.x;
    if (i < n) dst[i] = src[i];
}

__global__ void init_cursorA_kernel(const int* __restrict__ g, int RPB, int NR,
                                    int* __restrict__ cursorA)
{
    const int t = threadIdx.x;
    if (t < NBUCK) {
        int idx = t * RPB; if (idx > NR) idx = NR;
        cursorA[t] = g[idx];
    }
}

// ---- Pass A: bucket edges by vrow/RPB into dense staging; entry packed 8B:
//      [vrow:18b << 32 | col:16b << 16 | bf16(val)] ----
__global__ __launch_bounds__(256)
void bucket_stage_kernel(const int* __restrict__ r0, const int* __restrict__ c0, const float* __restrict__ v0,
                         const int* __restrict__ r1, const int* __restrict__ c1, const float* __restrict__ v1,
                         const int* __restrict__ rD, const int* __restrict__ cD, const float* __restrict__ vD,
                         int E, int ED, int N, int RPB,
                         int* __restrict__ cursorA, ull_t* __restrict__ stg)
{
    __shared__ int hcnt[NBUCK];
    __shared__ int hbase[NBUCK];
    const int tid = threadIdx.x;
    if (tid < NBUCK) hcnt[tid] = 0;
    __syncthreads();
    const long long base = (long long)blockIdx.x * 1024;
    const long long tot = 2LL * E + ED;
    int vr[4], rk[4], bk[4];
    unsigned pay[4];
    #pragma unroll
    for (int k = 0; k < 4; ++k) {
        const long long i = base + k * 256 + tid;
        vr[k] = -1;
        if (i < tot) {
            int cc; float vv;
            if (i < E)            { vr[k] = r0[i];                 cc = c0[i];            vv = v0[i]; }
            else if (i < 2LL * E) { vr[k] = N + r1[i - E];         cc = c1[i - E];        vv = v1[i - E]; }
            else                  { vr[k] = 2 * N + rD[i - 2LL * E]; cc = cD[i - 2LL * E]; vv = vD[i - 2LL * E]; }
            pay[k] = ((unsigned)cc << 16) | f2bf(vv);
            bk[k] = vr[k] / RPB;
            rk[k] = atomicAdd(&hcnt[bk[k]], 1);
        }
    }
    __syncthreads();
    if (tid < NBUCK) hbase[tid] = atomicAdd(&cursorA[tid], hcnt[tid]);
    __syncthreads();
    #pragma unroll
    for (int k = 0; k < 4; ++k) {
        if (vr[k] >= 0) {
            const int s = hbase[bk[k]] + rk[k];
            stg[s] = ((ull_t)(unsigned)vr[k] << 32) | pay[k];
        }
    }
}

// ---- Pass B: fine scatter of 4B payloads; nontemporal staging reads ----
__global__ __launch_bounds__(256)
void fine_scatter_kernel(const int* __restrict__ g, int RPB, int NR,
                         const ull_t* __restrict__ stg,
                         int* __restrict__ cursor, unsigned* __restrict__ ecv)
{
    const int b = blockIdx.x & (NBUCK - 1);
    int bsi = b * RPB;        if (bsi > NR) bsi = NR;
    int bei = (b + 1) * RPB;  if (bei > NR) bei = NR;
    const int bstart = g[bsi];
    const int bend   = g[bei];
    const int tid = threadIdx.x;
    for (int chunk = blockIdx.x >> 3; ; chunk += NCHUNK) {
        const int cbase = bstart + chunk * 1024;
        if (cbase >= bend) break;
        #pragma unroll
        for (int k = 0; k < 4; ++k) {
            const int i = cbase + k * 256 + tid;
            if (i < bend) {
                const ull_t t = __builtin_nontemporal_load(&stg[i]);
                const int vr = (int)(t >> 32);
                const int p = atomicAdd(&cursor[vr], 1);
                ecv[p] = (unsigned)t;
            }
        }
    }
}

// ---------------- feature-sliced CSR SpMM ----------------
// X is slice-major: [slice][Mrows][32 feats] bf16. slice = bid & (SLICES-1) so
// consecutive blocks (round-robin over XCDs) pin one 3.2 MB slice per XCD L2.
// 16 lanes per row (each lane = 2 feats), 16 rows per block.
template <int SLICES, bool RELU, bool F32OUT>
__global__ __launch_bounds__(256)
void spmm_sliced(const int* __restrict__ rp, const unsigned* __restrict__ ecv,
                 const ushort_t* __restrict__ X, int Mrows, int off,
                 void* __restrict__ Yv, const float* __restrict__ bias,
                 const float* __restrict__ ap, int n)
{
    constexpr int SH = (SLICES == 8) ? 3 : 2;
    constexpr int FTOT = SLICES * 32;
    const int slice = blockIdx.x & (SLICES - 1);
    const int r = (blockIdx.x >> SH) * 16 + (threadIdx.x >> 4);
    if (r >= n) return;
    const int l = threadIdx.x & 15;
    const int s = rp[r], e = rp[r + 1];
    const ushort_t* Xs = X + ((size_t)slice * Mrows + off) * 32 + 2 * l;
    float fx = 0.f, fy = 0.f;
    int j = s;
    for (; j + 3 < e; j += 4) {
        const unsigned e0 = ecv[j], e1 = ecv[j + 1], e2 = ecv[j + 2], e3 = ecv[j + 3];
        const unsigned x0 = *reinterpret_cast<const unsigned*>(Xs + (size_t)(e0 >> 16) * 32);
        const unsigned x1 = *reinterpret_cast<const unsigned*>(Xs + (size_t)(e1 >> 16) * 32);
        const unsigned x2 = *reinterpret_cast<const unsigned*>(Xs + (size_t)(e2 >> 16) * 32);
        const unsigned x3 = *reinterpret_cast<const unsigned*>(Xs + (size_t)(e3 >> 16) * 32);
        const float v0 = bf2f((ushort_t)e0), v1 = bf2f((ushort_t)e1);
        const float v2 = bf2f((ushort_t)e2), v3 = bf2f((ushort_t)e3);
        fx += v0 * bf2f((ushort_t)x0) + v1 * bf2f((ushort_t)x1)
            + v2 * bf2f((ushort_t)x2) + v3 * bf2f((ushort_t)x3);
        fy += v0 * bf2f((ushort_t)(x0 >> 16)) + v1 * bf2f((ushort_t)(x1 >> 16))
            + v2 * bf2f((ushort_t)(x2 >> 16)) + v3 * bf2f((ushort_t)(x3 >> 16));
    }
    for (; j < e; ++j) {
        const unsigned e0 = ecv[j];
        const unsigned x0 = *reinterpret_cast<const unsigned*>(Xs + (size_t)(e0 >> 16) * 32);
        const float v0 = bf2f((ushort_t)e0);
        fx += v0 * bf2f((ushort_t)x0);
        fy += v0 * bf2f((ushort_t)(x0 >> 16));
    }
    const float a = ap[0];
    const int f0 = slice * 32 + 2 * l;
    fx += bias[f0];     fy += bias[f0 + 1];
    fx = fx >= 0.f ? fx : a * fx;
    fy = fy >= 0.f ? fy : a * fy;
    if constexpr (RELU) { fx = fmaxf(fx, 0.f); fy = fmaxf(fy, 0.f); }
    if constexpr (F32OUT) {
        *reinterpret_cast<float2*>((float*)Yv + (size_t)r * FTOT + f0) = make_float2(fx, fy);
    } else {
        const unsigned o = ((unsigned)f2bf(fy) << 16) | f2bf(fx);
        *reinterpret_cast<unsigned*>((ushort_t*)Yv + (size_t)r * FTOT + f0) = o;
    }
}

// ---------------- gate precompute ----------------
__global__ void gate_pre_kernel(const float* __restrict__ G1w, const float* __restrict__ G1b,
                                const float* __restrict__ G2w, const float* __restrict__ G2b,
                                const float* __restrict__ G3w, const float* __restrict__ G3b,
                                float* __restrict__ U)
{
    const int h = threadIdx.x;  // 0..127
    float s1 = 0.f, s2 = 0.f;
    for (int g = 0; g < GATEC; ++g) {
        s1 += G1w[h * GATEC + g] * G3w[g];
        s2 += G2w[h * GATEC + g] * G3w[GATEC + g];
    }
    U[h] = s1;
    U[HDC + h] = s2;
    if (h == 0) {
        float c = G3b[0];
        for (int g = 0; g < GATEC; ++g)
            c += G1b[g] * G3w[g] + G2b[g] * G3w[GATEC + g];
        U[2 * HDC] = c;
        U[2 * HDC + 1] = G3w[2 * GATEC];
    }
}

// ---------------- beta ----------------
__global__ __launch_bounds__(256)
void beta_kernel(const float* __restrict__ h1, const float* __restrict__ h3,
                 const float* __restrict__ deg, const float* __restrict__ U,
                 float* __restrict__ beta, int n)
{
    const int i = blockIdx.x * blockDim.x + threadIdx.x;
    if (i >= n) return;
    const float c = U[2 * HDC], wd = U[2 * HDC + 1];
    float s = c + wd * deg[i];
    const float4* h1p = reinterpret_cast<const float4*>(h1 + (size_t)i * HDC);
    const float4* h3p = reinterpret_cast<const float4*>(h3 + (size_t)i * HDC);
    const float4* u1p = reinterpret_cast<const float4*>(U);
    const float4* u2p = reinterpret_cast<const float4*>(U + HDC);
    #pragma unroll 8
    for (int j = 0; j < HDC / 4; ++j) {
        const float4 a = h1p[j], b = u1p[j];
        s += a.x * b.x + a.y * b.y + a.z * b.z + a.w * b.w;
        const float4 a2 = h3p[j], b2 = u2p[j];
        s += a2.x * b2.x + a2.y * b2.y + a2.z * b2.z + a2.w * b2.w;
    }
    beta[i] = 1.f / (1.f + expf(-s));
}

extern "C" void kernel_launch(void* const* d_in, const int* in_sizes, int n_in,
                              void* d_out, int out_size, void* d_ws, size_t ws_size,
                              hipStream_t stream)
{
    const float* x1  = (const float*)d_in[0];
    const float* x2  = (const float*)d_in[1];
    const int*   a1r = (const int*)d_in[2];
    const int*   a1c = (const int*)d_in[3];
    const float* a1v = (const float*)d_in[4];
    const int*   a2r = (const int*)d_in[5];
    const int*   a2c = (const int*)d_in[6];
    const float* a2v = (const float*)d_in[7];
    const int*   dr  = (const int*)d_in[8];
    const int*   dc  = (const int*)d_in[9];
    const float* dv  = (const float*)d_in[10];
    const float* deg = (const float*)d_in[11];
    const float* W0  = (const float*)d_in[12];
    const float* b0  = (const float*)d_in[13];
    const float* a0  = (const float*)d_in[14];
    const float* W1  = (const float*)d_in[15];
    const float* b1  = (const float*)d_in[16];
    const float* a1p = (const float*)d_in[17];
    const float* G1w = (const float*)d_in[18];
    const float* G1b = (const float*)d_in[19];
    const float* G2w = (const float*)d_in[20];
    const float* G2b = (const float*)d_in[21];
    const float* G3w = (const float*)d_in[22];
    const float* G3b = (const float*)d_in[23];

    const int E  = in_sizes[2];
    const int ED = in_sizes[8];
    const int N  = in_sizes[11];
    const int IN = in_sizes[0] / N;   // 256
    const long long TOT = 2LL * E + ED;
    const int NR  = 3 * N;
    const int RPB = (NR + NBUCK - 1) / NBUCK;

    // ---- workspace bump allocator (256 B aligned) ----
    char* base = (char*)d_ws;
    size_t off = 0;
    auto alloc = [&](size_t bytes) -> char* {
        char* p = base + off;
        off += (bytes + 255) & ~(size_t)255;
        return p;
    };
    // XW12b: slice-major bf16 [8][2N][32] = x@W0 for x1 (rows 0..N) and x2 (rows N..2N)
    ushort_t* XW12b = (ushort_t*)alloc((size_t)2 * N * H2C * 2);
    // Region R: stg (TOT*8 B) -> Xb12 (2N*256 bf16) -> Bbb (N*256 bf16, row-major) + Cbb (slice-major [4][N][32])
    char* R = alloc((size_t)2 * N * H2C * 2);
    ull_t*    stg  = (ull_t*)R;
    ushort_t* Xb12 = (ushort_t*)R;
    ushort_t* Bbb  = (ushort_t*)R;
    ushort_t* Cbb  = (ushort_t*)(R + (size_t)N * H2C * 2);
    ushort_t* W0T  = (ushort_t*)alloc((size_t)H2C * H2C * 2);
    ushort_t* W1T  = (ushort_t*)alloc((size_t)HDC * H2C * 2);
    float*    U    = (float*)alloc(258 * 4);
    int*  cnt     = (int*)alloc((size_t)NR * 4);
    int*  g       = (int*)alloc((size_t)(NR + 1) * 4);
    int*  cursor  = (int*)alloc((size_t)NR * 4);
    int*  bsum    = (int*)alloc(1024 * 4);
    int*  cursorA = (int*)alloc(NBUCK * 4);
    unsigned* ecv = (unsigned*)alloc((size_t)TOT * 4);

    float* out  = (float*)d_out;
    float* h1   = out;
    float* h2   = out + 1 * (size_t)N * HDC;
    float* h3   = out + 2 * (size_t)N * HDC;
    float* h4   = out + 3 * (size_t)N * HDC;
    float* beta = out + 4 * (size_t)N * HDC;

    const int nb3 = (NR + 255) / 256;

    // ---- small precomputes ----
    gate_pre_kernel<<<1, HDC, 0, stream>>>(G1w, G1b, G2w, G2b, G3w, G3b, U);
    transpose_f2bf_kernel<<<dim3((H2C * H2C + 255) / 256), 256, 0, stream>>>(W0, W0T, H2C, H2C);
    transpose_f2bf_kernel<<<dim3((H2C * HDC + 255) / 256), 256, 0, stream>>>(W1, W1T, H2C, HDC);

    // ---- CSR build: hist + scan ----
    hipMemsetAsync(cnt, 0, (size_t)NR * 4, stream);
    hist3_kernel<<<dim3((unsigned)((TOT + 255) / 256)), 256, 0, stream>>>(a1r, a2r, dr, E, ED, N, cnt);
    block_sum_kernel<<<dim3(nb3), 256, 0, stream>>>(cnt, NR, bsum);
    scan_bsum_kernel<<<1, 64, 0, stream>>>(bsum, nb3);
    block_scan_kernel<<<dim3(nb3), 256, 0, stream>>>(cnt, NR, bsum, g, (int)TOT);
    copy_int_kernel<<<dim3(nb3), 256, 0, stream>>>(g, cursor, NR);

    // ---- two-phase scatter (packed 8B staging -> 4B ecv payloads) ----
    init_cursorA_kernel<<<1, 64, 0, stream>>>(g, RPB, NR, cursorA);
    bucket_stage_kernel<<<dim3((unsigned)((TOT + 1023) / 1024)), 256, 0, stream>>>(
        a1r, a1c, a1v, a2r, a2c, a2v, dr, dc, dv, E, ED, N, RPB, cursorA, stg);
    fine_scatter_kernel<<<dim3(NBUCK * NCHUNK), 256, 0, stream>>>(
        g, RPB, NR, stg, cursor, ecv);

    const int* rp1 = g;
    const int* rp2 = g + N;
    const int* rpD = g + 2 * N;

    // ---- x -> bf16 (both inputs), batched XW GEMM (2N rows, slice-major out) ----
    f2bf_pair_kernel<<<dim3(2048), 256, 0, stream>>>(x1, x2, Xb12, (long long)N * H2C / 4);
    gemm_bf16_mfma<true><<<dim3(H2C / 128, (2 * N + 127) / 128), 256, 0, stream>>>(
        Xb12, W0T, XW12b, 2 * N, H2C, IN);

    const int spgrid8 = 8 * ((N + 15) / 16);
    const int spgrid4 = 4 * ((N + 15) / 16);

    auto run_branch = [&](const int* rp, int xoff, float* hout) {
        // spmm1: gather XW12b slice-major [8][2N][32], rows offset xoff; out Bbb row-major
        spmm_sliced<8, true, false><<<dim3(spgrid8), 256, 0, stream>>>(
            rp, ecv, XW12b, 2 * N, xoff, Bbb, b0, a0, N);
        // layer-2 GEMM: Cbb = Bbb @ W1 (slice-major out [4][N][32])
        gemm_bf16_mfma<true><<<dim3(HDC / 128, (N + 127) / 128), 256, 0, stream>>>(
            Bbb, W1T, Cbb, N, HDC, H2C);
        // spmm2: gather Cbb slice-major; out hout row-major fp32
        spmm_sliced<4, false, true><<<dim3(spgrid4), 256, 0, stream>>>(
            rp, ecv, Cbb, N, 0, hout, b1, a1p, N);
    };

    run_branch(rp1, 0, h1);
    run_branch(rp2, 0, h3);
    run_branch(rpD, 0, h4);
    run_branch(rp1, N, h2);

    beta_kernel<<<dim3((N + 255) / 256), 256, 0, stream>>>(h1, h3, deg, U, beta, N);
}

// Round 8
// 662.918 us; speedup vs baseline: 1.2573x; 1.2573x over previous
//
#include <hip/hip_runtime.h>
#include <hip/hip_bf16.h>

#define H2C 256   // 2*hidden
#define HDC 128   // hidden
#define GATEC 64
#define FBSH 9        // 512 rows per fine bucket
#define NBF 320       // padded fine-bucket count (293 used)
#define EPB 8192      // edges per block in pass A
#define CAPB 16384    // pass-B LDS payload capacity (edges)

typedef unsigned short ushort_t;
typedef unsigned long long ull_t;
typedef __attribute__((ext_vector_type(8))) __bf16 bf16x8;
typedef __attribute__((ext_vector_type(4))) float f32x4;

__device__ inline float bf2f(unsigned short v) {
    union { unsigned u; float f; } t; t.u = ((unsigned)v) << 16; return t.f;
}
__device__ inline unsigned short f2bf(float v) {
    __hip_bfloat16 b = __float2bfloat16(v);
    return *reinterpret_cast<unsigned short*>(&b);
}

__device__ inline void gload_lds16(const void* g, void* l) {
    __builtin_amdgcn_global_load_lds(
        (const __attribute__((address_space(1))) unsigned int*)g,
        (__attribute__((address_space(3))) unsigned int*)l, 16, 0, 0);
}

// ---------------- bf16 MFMA GEMM: C[M,Nn] = A[M,K] @ BT^T (row-major out) ----------------
__global__ __launch_bounds__(256)
void gemm_bf16_mfma(const ushort_t* __restrict__ A, const ushort_t* __restrict__ BT,
                    ushort_t* __restrict__ C, int M, int Nn, int K)
{
    __shared__ ushort_t Alds[128 * 64];
    __shared__ ushort_t Blds[128 * 64];
    const int tid  = threadIdx.x;
    const int w    = tid >> 6;
    const int lane = tid & 63;
    const int wr   = w >> 1;
    const int wc   = w & 1;
    const int bm   = blockIdx.y * 128;
    const int bn   = blockIdx.x * 128;

    f32x4 acc[4][4] = {};

    for (int k0 = 0; k0 < K; k0 += 64) {
        #pragma unroll
        for (int i = 0; i < 4; ++i) {
            const int lin = i * 256 + tid;
            const int r = lin >> 3, p = lin & 7;
            int rm = bm + r; if (rm >= M) rm = M - 1;
            const ushort_t* ga = A + (size_t)rm * K + k0 + ((p ^ (r & 7)) << 3);
            gload_lds16(ga, &Alds[i * 2048 + w * 512]);
        }
        #pragma unroll
        for (int i = 0; i < 4; ++i) {
            const int lin = i * 256 + tid;
            const int r = lin >> 3, p = lin & 7;
            const ushort_t* gb = BT + (size_t)(bn + r) * K + k0 + ((p ^ (r & 7)) << 3);
            gload_lds16(gb, &Blds[i * 2048 + w * 512]);
        }
        __syncthreads();
        #pragma unroll
        for (int kk = 0; kk < 2; ++kk) {
            bf16x8 af[4], bfr[4];
            #pragma unroll
            for (int m = 0; m < 4; ++m) {
                const int r = wr * 64 + m * 16 + (lane & 15);
                const int s = kk * 4 + (lane >> 4);
                af[m] = *reinterpret_cast<const bf16x8*>(&Alds[r * 64 + ((s ^ (r & 7)) << 3)]);
            }
            #pragma unroll
            for (int n = 0; n < 4; ++n) {
                const int r = wc * 64 + n * 16 + (lane & 15);
                const int s = kk * 4 + (lane >> 4);
                bfr[n] = *reinterpret_cast<const bf16x8*>(&Blds[r * 64 + ((s ^ (r & 7)) << 3)]);
            }
            #pragma unroll
            for (int m = 0; m < 4; ++m)
                #pragma unroll
                for (int n = 0; n < 4; ++n)
                    acc[m][n] = __builtin_amdgcn_mfma_f32_16x16x32_bf16(
                        af[m], bfr[n], acc[m][n], 0, 0, 0);
        }
        __syncthreads();
    }

    #pragma unroll
    for (int m = 0; m < 4; ++m) {
        const int row0 = bm + wr * 64 + m * 16 + ((lane >> 4) << 2);
        #pragma unroll
        for (int n = 0; n < 4; ++n) {
            const int col = bn + wc * 64 + n * 16 + (lane & 15);
            #pragma unroll
            for (int q = 0; q < 4; ++q) {
                const int row = row0 + q;
                if (row < M) C[(size_t)row * Nn + col] = f2bf(acc[m][n][q]);
            }
        }
    }
}

// ---------------- fp32 -> bf16 convert, two sources into one buffer ----------------
__global__ __launch_bounds__(256)
void f2bf_pair_kernel(const float* __restrict__ in1, const float* __restrict__ in2,
                      ushort_t* __restrict__ out, long long n4each)
{
    long long i = (long long)blockIdx.x * blockDim.x + threadIdx.x;
    const long long stride = (long long)gridDim.x * blockDim.x;
    for (; i < 2 * n4each; i += stride) {
        const float* src = (i < n4each) ? in1 : in2;
        const long long k = (i < n4each) ? i : i - n4each;
        const float4 v = reinterpret_cast<const float4*>(src)[k];
        ushort4 o;
        o.x = f2bf(v.x); o.y = f2bf(v.y); o.z = f2bf(v.z); o.w = f2bf(v.w);
        reinterpret_cast<ushort4*>(out)[i] = o;
    }
}

// ---------------- W[R,C] -> bf16 WT[C,R] ----------------
__global__ __launch_bounds__(256)
void transpose_f2bf_kernel(const float* __restrict__ W, ushort_t* __restrict__ WT, int R, int Ccols)
{
    const int i = blockIdx.x * blockDim.x + threadIdx.x;
    if (i >= R * Ccols) return;
    const int c = i / R, r = i % R;
    WT[(size_t)c * R + r] = f2bf(W[(size_t)r * Ccols + c]);
}

// ---------------- CSR build: histogram + scan over 3 concatenated adjacencies ----------------
__global__ __launch_bounds__(256)
void hist3_kernel(const int* __restrict__ r0, const int* __restrict__ r1,
                  const int* __restrict__ rD, int E, int ED, int N, int* __restrict__ cnt)
{
    const long long i = (long long)blockIdx.x * blockDim.x + threadIdx.x;
    const long long tot = 2LL * E + ED;
    if (i >= tot) return;
    int idx;
    if (i < E)            idx = r0[i];
    else if (i < 2LL * E) idx = N + r1[i - E];
    else                  idx = 2 * N + rD[i - 2LL * E];
    atomicAdd(&cnt[idx], 1);
}

__global__ __launch_bounds__(256)
void block_sum_kernel(const int* __restrict__ cnt, int n, int* __restrict__ bsum)
{
    __shared__ int s[256];
    const int tid = threadIdx.x;
    const int i = blockIdx.x * 256 + tid;
    s[tid] = (i < n) ? cnt[i] : 0;
    __syncthreads();
    for (int o = 128; o > 0; o >>= 1) {
        if (tid < o) s[tid] += s[tid + o];
        __syncthreads();
    }
    if (tid == 0) bsum[blockIdx.x] = s[0];
}

__global__ void scan_bsum_kernel(int* __restrict__ bsum, int nb)
{
    if (threadIdx.x == 0) {
        int acc = 0;
        for (int b = 0; b < nb; ++b) { int t = bsum[b]; bsum[b] = acc; acc += t; }
    }
}

__global__ __launch_bounds__(256)
void block_scan_kernel(const int* __restrict__ cnt, int n, const int* __restrict__ bsum,
                       int* __restrict__ g, int tot)
{
    __shared__ int sh[256];
    const int tid = threadIdx.x;
    const int i = blockIdx.x * 256 + tid;
    const int v = (i < n) ? cnt[i] : 0;
    sh[tid] = v;
    __syncthreads();
    for (int o = 1; o < 256; o <<= 1) {
        int t = 0;
        if (tid >= o) t = sh[tid - o];
        __syncthreads();
        sh[tid] += t;
        __syncthreads();
    }
    if (i < n) g[i] = bsum[blockIdx.x] + sh[tid] - v;  // exclusive
    if (i == 0) g[n] = tot;
}

__global__ __launch_bounds__(256)
void copy_int_kernel(const int* __restrict__ src, int* __restrict__ dst, int n)
{
    const int i = blockIdx.x * 256 + threadIdx.x;
    if (i < n) dst[i] = src[i];
}

// gcur[fb] = rp[min(fb*512, NR)] : staging region for bucket fb == final CSR range
__global__ void init_gcur_kernel(const int* __restrict__ g, int NR, int* __restrict__ gcur)
{
    const int t = blockIdx.x * blockDim.x + threadIdx.x;
    if (t < NBF) {
        int idx = t << FBSH; if (idx > NR) idx = NR;
        gcur[t] = g[idx];
    }
}

// ---- Pass A: chunked bucket staging. Per-block LDS histogram over 293 fine buckets,
//      per-bucket run reservation -> dense run writes (entry = vrow<<32|col<<16|bf16(val)).
__global__ __launch_bounds__(256)
void bucket_stage_kernel(const int* __restrict__ r0, const int* __restrict__ c0, const float* __restrict__ v0,
                         const int* __restrict__ r1, const int* __restrict__ c1, const float* __restrict__ v1,
                         const int* __restrict__ rD, const int* __restrict__ cD, const float* __restrict__ vD,
                         int E, int ED, int N,
                         int* __restrict__ gcur, ull_t* __restrict__ stg)
{
    __shared__ int hcnt[NBF];
    __shared__ int hbase[NBF];
    const int tid = threadIdx.x;
    for (int t = tid; t < NBF; t += 256) hcnt[t] = 0;
    __syncthreads();
    const long long tot = 2LL * E + ED;
    const long long base = (long long)blockIdx.x * EPB;
    // pass 1: histogram
    #pragma unroll
    for (int k = 0; k < EPB / 256; ++k) {
        const long long i = base + k * 256 + tid;
        if (i < tot) {
            int vr;
            if (i < E)            vr = r0[i];
            else if (i < 2LL * E) vr = N + r1[i - E];
            else                  vr = 2 * N + rD[i - 2LL * E];
            atomicAdd(&hcnt[vr >> FBSH], 1);
        }
    }
    __syncthreads();
    for (int t = tid; t < NBF; t += 256) {
        const int c = hcnt[t];
        hbase[t] = c ? atomicAdd(&gcur[t], c) : 0;
        hcnt[t] = 0;  // reuse as local cursor
    }
    __syncthreads();
    // pass 2: place into reserved runs
    #pragma unroll
    for (int k = 0; k < EPB / 256; ++k) {
        const long long i = base + k * 256 + tid;
        if (i < tot) {
            int vr, cc; float vv;
            if (i < E)            { vr = r0[i];                 cc = c0[i];            vv = v0[i]; }
            else if (i < 2LL * E) { vr = N + r1[i - E];         cc = c1[i - E];        vv = v1[i - E]; }
            else                  { vr = 2 * N + rD[i - 2LL * E]; cc = cD[i - 2LL * E]; vv = vD[i - 2LL * E]; }
            const int fb = vr >> FBSH;
            const int p = hbase[fb] + atomicAdd(&hcnt[fb], 1);
            stg[p] = ((ull_t)(unsigned)vr << 32) | ((unsigned)cc << 16) | f2bf(vv);
        }
    }
}

// ---- Pass B: per-bucket LDS counting sort; fully coalesced ecv writes ----
__global__ __launch_bounds__(256)
void sort_bucket_kernel(const int* __restrict__ rp, int NR,
                        const ull_t* __restrict__ stg,
                        int* __restrict__ cursor, unsigned* __restrict__ ecv)
{
    __shared__ int lcur[512];
    __shared__ unsigned pay[CAPB];
    const int b = blockIdx.x;
    const int r0 = b << FBSH;
    if (r0 >= NR) return;
    int r1 = r0 + (1 << FBSH); if (r1 > NR) r1 = NR;
    const int base = rp[r0], end = rp[r1];
    const int bsz = end - base;
    const int tid = threadIdx.x;
    if (bsz <= CAPB) {
        for (int t = tid; t < r1 - r0; t += 256) lcur[t] = rp[r0 + t] - base;
        __syncthreads();
        for (int i = base + tid; i < end; i += 256) {
            const ull_t t = stg[i];
            const int lr = (int)(t >> 32) - r0;
            const int p = atomicAdd(&lcur[lr], 1);
            pay[p] = (unsigned)t;
        }
        __syncthreads();
        for (int i = tid; i < bsz; i += 256)
            ecv[base + i] = pay[i];
    } else {
        // overflow fallback: global atomic scatter (cursor pre-initialized to rp)
        for (int i = base + tid; i < end; i += 256) {
            const ull_t t = stg[i];
            const int vr = (int)(t >> 32);
            const int p = atomicAdd(&cursor[vr], 1);
            ecv[p] = (unsigned)t;
        }
    }
}

// ---------------- CSR SpMM, F=256: 1 row/wave, 2 edges/iter, 16B gathers ----------------
__global__ __launch_bounds__(256)
void spmm_f256(const int* __restrict__ rp, const unsigned* __restrict__ ecv,
               const ushort_t* __restrict__ X, ushort_t* __restrict__ Y,
               const float* __restrict__ bias, const float* __restrict__ ap, int n)
{
    const int r = blockIdx.x * 4 + (threadIdx.x >> 6);
    if (r >= n) return;
    const int lane = threadIdx.x & 63;
    const int half = lane >> 5;    // edge parity
    const int l    = lane & 31;    // 16B chunk (8 bf16 feats)
    const int s = rp[r], e = rp[r + 1];
    float acc[8] = {};
    #pragma unroll 2
    for (int j = s + half; j < e; j += 2) {
        const unsigned ev = ecv[j];
        const float v = bf2f((ushort_t)ev);
        const uint4 x = *reinterpret_cast<const uint4*>(X + (size_t)(ev >> 16) * H2C + l * 8);
        acc[0] += v * bf2f((ushort_t)x.x); acc[1] += v * bf2f((ushort_t)(x.x >> 16));
        acc[2] += v * bf2f((ushort_t)x.y); acc[3] += v * bf2f((ushort_t)(x.y >> 16));
        acc[4] += v * bf2f((ushort_t)x.z); acc[5] += v * bf2f((ushort_t)(x.z >> 16));
        acc[6] += v * bf2f((ushort_t)x.w); acc[7] += v * bf2f((ushort_t)(x.w >> 16));
    }
    #pragma unroll
    for (int k = 0; k < 8; ++k) acc[k] += __shfl_xor(acc[k], 32);
    if (half == 0) {
        const float a = ap[0];
        const int f0 = l * 8;
        const float4 b0v = *reinterpret_cast<const float4*>(bias + f0);
        const float4 b1v = *reinterpret_cast<const float4*>(bias + f0 + 4);
        const float bb[8] = {b0v.x, b0v.y, b0v.z, b0v.w, b1v.x, b1v.y, b1v.z, b1v.w};
        unsigned o[4];
        #pragma unroll
        for (int k = 0; k < 8; k += 2) {
            float tx = acc[k] + bb[k];
            float ty = acc[k + 1] + bb[k + 1];
            tx = tx >= 0.f ? tx : a * tx;  ty = ty >= 0.f ? ty : a * ty;
            tx = fmaxf(tx, 0.f);           ty = fmaxf(ty, 0.f);
            o[k >> 1] = ((unsigned)f2bf(ty) << 16) | f2bf(tx);
        }
        *reinterpret_cast<uint4*>(Y + (size_t)r * H2C + f0) = make_uint4(o[0], o[1], o[2], o[3]);
    }
}

// ---------------- CSR SpMM, F=128: 1 row/wave, 4 edges/iter, 16B gathers, fp32 out ----------------
__global__ __launch_bounds__(256)
void spmm_f128(const int* __restrict__ rp, const unsigned* __restrict__ ecv,
               const ushort_t* __restrict__ X, float* __restrict__ Y,
               const float* __restrict__ bias, const float* __restrict__ ap, int n)
{
    const int r = blockIdx.x * 4 + (threadIdx.x >> 6);
    if (r >= n) return;
    const int lane = threadIdx.x & 63;
    const int q = lane >> 4;   // edge in quad
    const int l = lane & 15;   // 16B chunk
    const int s = rp[r], e = rp[r + 1];
    float acc[8] = {};
    #pragma unroll 2
    for (int j = s + q; j < e; j += 4) {
        const unsigned ev = ecv[j];
        const float v = bf2f((ushort_t)ev);
        const uint4 x = *reinterpret_cast<const uint4*>(X + (size_t)(ev >> 16) * HDC + l * 8);
        acc[0] += v * bf2f((ushort_t)x.x); acc[1] += v * bf2f((ushort_t)(x.x >> 16));
        acc[2] += v * bf2f((ushort_t)x.y); acc[3] += v * bf2f((ushort_t)(x.y >> 16));
        acc[4] += v * bf2f((ushort_t)x.z); acc[5] += v * bf2f((ushort_t)(x.z >> 16));
        acc[6] += v * bf2f((ushort_t)x.w); acc[7] += v * bf2f((ushort_t)(x.w >> 16));
    }
    #pragma unroll
    for (int k = 0; k < 8; ++k) {
        acc[k] += __shfl_xor(acc[k], 16);
        acc[k] += __shfl_xor(acc[k], 32);
    }
    if (q == 0) {
        const float a = ap[0];
        const int f0 = l * 8;
        const float4 b0v = *reinterpret_cast<const float4*>(bias + f0);
        const float4 b1v = *reinterpret_cast<const float4*>(bias + f0 + 4);
        const float bb[8] = {b0v.x, b0v.y, b0v.z, b0v.w, b1v.x, b1v.y, b1v.z, b1v.w};
        float o[8];
        #pragma unroll
        for (int k = 0; k < 8; ++k) {
            float t = acc[k] + bb[k];
            o[k] = t >= 0.f ? t : a * t;
        }
        *reinterpret_cast<float4*>(Y + (size_t)r * HDC + f0)     = make_float4(o[0], o[1], o[2], o[3]);
        *reinterpret_cast<float4*>(Y + (size_t)r * HDC + f0 + 4) = make_float4(o[4], o[5], o[6], o[7]);
    }
}

// ---------------- gate precompute ----------------
__global__ void gate_pre_kernel(const float* __restrict__ G1w, const float* __restrict__ G1b,
                                const float* __restrict__ G2w, const float* __restrict__ G2b,
                                const float* __restrict__ G3w, const float* __restrict__ G3b,
                                float* __restrict__ U)
{
    const int h = threadIdx.x;  // 0..127
    float s1 = 0.f, s2 = 0.f;
    for (int g = 0; g < GATEC; ++g) {
        s1 += G1w[h * GATEC + g] * G3w[g];
        s2 += G2w[h * GATEC + g] * G3w[GATEC + g];
    }
    U[h] = s1;
    U[HDC + h] = s2;
    if (h == 0) {
        float c = G3b[0];
        for (int g = 0; g < GATEC; ++g)
            c += G1b[g] * G3w[g] + G2b[g] * G3w[GATEC + g];
        U[2 * HDC] = c;
        U[2 * HDC + 1] = G3w[2 * GATEC];
    }
}

// ---------------- beta ----------------
__global__ __launch_bounds__(256)
void beta_kernel(const float* __restrict__ h1, const float* __restrict__ h3,
                 const float* __restrict__ deg, const float* __restrict__ U,
                 float* __restrict__ beta, int n)
{
    const int i = blockIdx.x * blockDim.x + threadIdx.x;
    if (i >= n) return;
    const float c = U[2 * HDC], wd = U[2 * HDC + 1];
    float s = c + wd * deg[i];
    const float4* h1p = reinterpret_cast<const float4*>(h1 + (size_t)i * HDC);
    const float4* h3p = reinterpret_cast<const float4*>(h3 + (size_t)i * HDC);
    const float4* u1p = reinterpret_cast<const float4*>(U);
    const float4* u2p = reinterpret_cast<const float4*>(U + HDC);
    #pragma unroll 8
    for (int j = 0; j < HDC / 4; ++j) {
        const float4 a = h1p[j], b = u1p[j];
        s += a.x * b.x + a.y * b.y + a.z * b.z + a.w * b.w;
        const float4 a2 = h3p[j], b2 = u2p[j];
        s += a2.x * b2.x + a2.y * b2.y + a2.z * b2.z + a2.w * b2.w;
    }
    beta[i] = 1.f / (1.f + expf(-s));
}

extern "C" void kernel_launch(void* const* d_in, const int* in_sizes, int n_in,
                              void* d_out, int out_size, void* d_ws, size_t ws_size,
                              hipStream_t stream)
{
    const float* x1  = (const float*)d_in[0];
    const float* x2  = (const float*)d_in[1];
    const int*   a1r = (const int*)d_in[2];
    const int*   a1c = (const int*)d_in[3];
    const float* a1v = (const float*)d_in[4];
    const int*   a2r = (const int*)d_in[5];
    const int*   a2c = (const int*)d_in[6];
    const float* a2v = (const float*)d_in[7];
    const int*   dr  = (const int*)d_in[8];
    const int*   dc  = (const int*)d_in[9];
    const float* dv  = (const float*)d_in[10];
    const float* deg = (const float*)d_in[11];
    const float* W0  = (const float*)d_in[12];
    const float* b0  = (const float*)d_in[13];
    const float* a0  = (const float*)d_in[14];
    const float* W1  = (const float*)d_in[15];
    const float* b1  = (const float*)d_in[16];
    const float* a1p = (const float*)d_in[17];
    const float* G1w = (const float*)d_in[18];
    const float* G1b = (const float*)d_in[19];
    const float* G2w = (const float*)d_in[20];
    const float* G2b = (const float*)d_in[21];
    const float* G3w = (const float*)d_in[22];
    const float* G3b = (const float*)d_in[23];

    const int E  = in_sizes[2];
    const int ED = in_sizes[8];
    const int N  = in_sizes[11];
    const int IN = in_sizes[0] / N;   // 256
    const long long TOT = 2LL * E + ED;
    const int NR  = 3 * N;
    const int NBUSED = (NR + (1 << FBSH) - 1) >> FBSH;   // 293

    // ---- workspace bump allocator (256 B aligned) ----
    char* base = (char*)d_ws;
    size_t off = 0;
    auto alloc = [&](size_t bytes) -> char* {
        char* p = base + off;
        off += (bytes + 255) & ~(size_t)255;
        return p;
    };
    // XW12b: row-major bf16 [2N][256] = [x1@W0 ; x2@W0]
    ushort_t* XW12b = (ushort_t*)alloc((size_t)2 * N * H2C * 2);
    // Region R: stg (TOT*8 B) -> Xb12 (2N*256 bf16) -> Bbb (N*256 bf16) + Cbb (N*128 bf16)
    char* R = alloc((size_t)2 * N * H2C * 2);
    ull_t*    stg  = (ull_t*)R;
    ushort_t* Xb12 = (ushort_t*)R;
    ushort_t* Bbb  = (ushort_t*)R;
    ushort_t* Cbb  = (ushort_t*)(R + (size_t)N * H2C * 2);
    ushort_t* W0T  = (ushort_t*)alloc((size_t)H2C * H2C * 2);
    ushort_t* W1T  = (ushort_t*)alloc((size_t)HDC * H2C * 2);
    float*    U    = (float*)alloc(258 * 4);
    int*  cnt     = (int*)alloc((size_t)NR * 4);
    int*  g       = (int*)alloc((size_t)(NR + 1) * 4);
    int*  cursor  = (int*)alloc((size_t)NR * 4);
    int*  bsum    = (int*)alloc(1024 * 4);
    int*  gcur    = (int*)alloc(NBF * 4);
    unsigned* ecv = (unsigned*)alloc((size_t)TOT * 4);

    float* out  = (float*)d_out;
    float* h1   = out;
    float* h2   = out + 1 * (size_t)N * HDC;
    float* h3   = out + 2 * (size_t)N * HDC;
    float* h4   = out + 3 * (size_t)N * HDC;
    float* beta = out + 4 * (size_t)N * HDC;

    const int nb3 = (NR + 255) / 256;

    // ---- small precomputes ----
    gate_pre_kernel<<<1, HDC, 0, stream>>>(G1w, G1b, G2w, G2b, G3w, G3b, U);
    transpose_f2bf_kernel<<<dim3((H2C * H2C + 255) / 256), 256, 0, stream>>>(W0, W0T, H2C, H2C);
    transpose_f2bf_kernel<<<dim3((H2C * HDC + 255) / 256), 256, 0, stream>>>(W1, W1T, H2C, HDC);

    // ---- CSR build: hist + scan ----
    hipMemsetAsync(cnt, 0, (size_t)NR * 4, stream);
    hist3_kernel<<<dim3((unsigned)((TOT + 255) / 256)), 256, 0, stream>>>(a1r, a2r, dr, E, ED, N, cnt);
    block_sum_kernel<<<dim3(nb3), 256, 0, stream>>>(cnt, NR, bsum);
    scan_bsum_kernel<<<1, 64, 0, stream>>>(bsum, nb3);
    block_scan_kernel<<<dim3(nb3), 256, 0, stream>>>(cnt, NR, bsum, g, (int)TOT);
    copy_int_kernel<<<dim3(nb3), 256, 0, stream>>>(g, cursor, NR);   // fallback cursors
    init_gcur_kernel<<<dim3(2), 256, 0, stream>>>(g, NR, gcur);

    // ---- two-pass sort: chunked bucket stage -> LDS counting sort ----
    bucket_stage_kernel<<<dim3((unsigned)((TOT + EPB - 1) / EPB)), 256, 0, stream>>>(
        a1r, a1c, a1v, a2r, a2c, a2v, dr, dc, dv, E, ED, N, gcur, stg);
    sort_bucket_kernel<<<dim3(NBUSED), 256, 0, stream>>>(g, NR, stg, cursor, ecv);

    const int* rp1 = g;
    const int* rp2 = g + N;
    const int* rpD = g + 2 * N;

    // ---- x -> bf16 (both inputs), batched XW GEMM (2N rows) ----
    f2bf_pair_kernel<<<dim3(2048), 256, 0, stream>>>(x1, x2, Xb12, (long long)N * H2C / 4);
    gemm_bf16_mfma<<<dim3(H2C / 128, (2 * N + 127) / 128), 256, 0, stream>>>(
        Xb12, W0T, XW12b, 2 * N, H2C, IN);

    auto run_branch = [&](const int* rp, const ushort_t* Xsrc, float* hout) {
        spmm_f256<<<dim3((N + 3) / 4), 256, 0, stream>>>(rp, ecv, Xsrc, Bbb, b0, a0, N);
        gemm_bf16_mfma<<<dim3(HDC / 128, (N + 127) / 128), 256, 0, stream>>>(
            Bbb, W1T, Cbb, N, HDC, H2C);
        spmm_f128<<<dim3((N + 3) / 4), 256, 0, stream>>>(rp, ecv, Cbb, hout, b1, a1p, N);
    };

    const ushort_t* XW1b = XW12b;
    const ushort_t* XW2b = XW12b + (size_t)N * H2C;

    run_branch(rp1, XW1b, h1);
    run_branch(rp2, XW1b, h3);
    run_branch(rpD, XW1b, h4);
    run_branch(rp1, XW2b, h2);

    beta_kernel<<<dim3((N + 255) / 256), 256, 0, stream>>>(h1, h3, deg, U, beta, N);
}

// Round 9
// 553.188 us; speedup vs baseline: 1.5068x; 1.1984x over previous
//
#include <hip/hip_runtime.h>
#include <hip/hip_bf16.h>

#define H2C 256   // 2*hidden
#define HDC 128   // hidden
#define GATEC 64
#define FBSH 9        // 512 rows per fine bucket
#define NBF 320       // padded fine-bucket count (293 used)
#define EPB 8192      // edges per block in stage pass
#define EPBH 2048     // edges per block in bucket-hist pass
#define CAPB 10240    // sort-pass LDS payload capacity (edges); avg bucket ~6963

typedef unsigned short ushort_t;
typedef unsigned long long ull_t;
typedef __attribute__((ext_vector_type(8))) __bf16 bf16x8;
typedef __attribute__((ext_vector_type(4))) float f32x4;

__device__ inline float bf2f(unsigned short v) {
    union { unsigned u; float f; } t; t.u = ((unsigned)v) << 16; return t.f;
}
__device__ inline unsigned short f2bf(float v) {
    __hip_bfloat16 b = __float2bfloat16(v);
    return *reinterpret_cast<unsigned short*>(&b);
}

__device__ inline void gload_lds16(const void* g, void* l) {
    __builtin_amdgcn_global_load_lds(
        (const __attribute__((address_space(1))) unsigned int*)g,
        (__attribute__((address_space(3))) unsigned int*)l, 16, 0, 0);
}

// ---------------- bf16 MFMA GEMM: C[M,Nn] = A[M,K] @ BT^T (row-major out) ----------------
__global__ __launch_bounds__(256)
void gemm_bf16_mfma(const ushort_t* __restrict__ A, const ushort_t* __restrict__ BT,
                    ushort_t* __restrict__ C, int M, int Nn, int K)
{
    __shared__ ushort_t Alds[128 * 64];
    __shared__ ushort_t Blds[128 * 64];
    const int tid  = threadIdx.x;
    const int w    = tid >> 6;
    const int lane = tid & 63;
    const int wr   = w >> 1;
    const int wc   = w & 1;
    const int bm   = blockIdx.y * 128;
    const int bn   = blockIdx.x * 128;

    f32x4 acc[4][4] = {};

    for (int k0 = 0; k0 < K; k0 += 64) {
        #pragma unroll
        for (int i = 0; i < 4; ++i) {
            const int lin = i * 256 + tid;
            const int r = lin >> 3, p = lin & 7;
            int rm = bm + r; if (rm >= M) rm = M - 1;
            const ushort_t* ga = A + (size_t)rm * K + k0 + ((p ^ (r & 7)) << 3);
            gload_lds16(ga, &Alds[i * 2048 + w * 512]);
        }
        #pragma unroll
        for (int i = 0; i < 4; ++i) {
            const int lin = i * 256 + tid;
            const int r = lin >> 3, p = lin & 7;
            const ushort_t* gb = BT + (size_t)(bn + r) * K + k0 + ((p ^ (r & 7)) << 3);
            gload_lds16(gb, &Blds[i * 2048 + w * 512]);
        }
        __syncthreads();
        #pragma unroll
        for (int kk = 0; kk < 2; ++kk) {
            bf16x8 af[4], bfr[4];
            #pragma unroll
            for (int m = 0; m < 4; ++m) {
                const int r = wr * 64 + m * 16 + (lane & 15);
                const int s = kk * 4 + (lane >> 4);
                af[m] = *reinterpret_cast<const bf16x8*>(&Alds[r * 64 + ((s ^ (r & 7)) << 3)]);
            }
            #pragma unroll
            for (int n = 0; n < 4; ++n) {
                const int r = wc * 64 + n * 16 + (lane & 15);
                const int s = kk * 4 + (lane >> 4);
                bfr[n] = *reinterpret_cast<const bf16x8*>(&Blds[r * 64 + ((s ^ (r & 7)) << 3)]);
            }
            #pragma unroll
            for (int m = 0; m < 4; ++m)
                #pragma unroll
                for (int n = 0; n < 4; ++n)
                    acc[m][n] = __builtin_amdgcn_mfma_f32_16x16x32_bf16(
                        af[m], bfr[n], acc[m][n], 0, 0, 0);
        }
        __syncthreads();
    }

    #pragma unroll
    for (int m = 0; m < 4; ++m) {
        const int row0 = bm + wr * 64 + m * 16 + ((lane >> 4) << 2);
        #pragma unroll
        for (int n = 0; n < 4; ++n) {
            const int col = bn + wc * 64 + n * 16 + (lane & 15);
            #pragma unroll
            for (int q = 0; q < 4; ++q) {
                const int row = row0 + q;
                if (row < M) C[(size_t)row * Nn + col] = f2bf(acc[m][n][q]);
            }
        }
    }
}

// ---------------- fp32 -> bf16 convert, two sources into one buffer ----------------
__global__ __launch_bounds__(256)
void f2bf_pair_kernel(const float* __restrict__ in1, const float* __restrict__ in2,
                      ushort_t* __restrict__ out, long long n4each)
{
    long long i = (long long)blockIdx.x * blockDim.x + threadIdx.x;
    const long long stride = (long long)gridDim.x * blockDim.x;
    for (; i < 2 * n4each; i += stride) {
        const float* src = (i < n4each) ? in1 : in2;
        const long long k = (i < n4each) ? i : i - n4each;
        const float4 v = reinterpret_cast<const float4*>(src)[k];
        ushort4 o;
        o.x = f2bf(v.x); o.y = f2bf(v.y); o.z = f2bf(v.z); o.w = f2bf(v.w);
        reinterpret_cast<ushort4*>(out)[i] = o;
    }
}

// ---------------- W[R,C] -> bf16 WT[C,R] ----------------
__global__ __launch_bounds__(256)
void transpose_f2bf_kernel(const float* __restrict__ W, ushort_t* __restrict__ WT, int R, int Ccols)
{
    const int i = blockIdx.x * blockDim.x + threadIdx.x;
    if (i >= R * Ccols) return;
    const int c = i / R, r = i % R;
    WT[(size_t)c * R + r] = f2bf(W[(size_t)r * Ccols + c]);
}

// ---------------- bucket-level histogram (320 buckets, LDS-aggregated) ----------------
__global__ __launch_bounds__(256)
void bucket_hist_kernel(const int* __restrict__ r0, const int* __restrict__ r1_,
                        const int* __restrict__ rD, int E, int ED, int N,
                        int* __restrict__ bcnt)
{
    __shared__ int h[NBF];
    const int tid = threadIdx.x;
    for (int t = tid; t < NBF; t += 256) h[t] = 0;
    __syncthreads();
    const long long tot = 2LL * E + ED;
    const long long base = (long long)blockIdx.x * EPBH;
    #pragma unroll
    for (int k = 0; k < EPBH / 256; ++k) {
        const long long i = base + k * 256 + tid;
        if (i < tot) {
            int vr;
            if (i < E)            vr = r0[i];
            else if (i < 2LL * E) vr = N + r1_[i - E];
            else                  vr = 2 * N + rD[i - 2LL * E];
            atomicAdd(&h[vr >> FBSH], 1);
        }
    }
    __syncthreads();
    for (int t = tid; t < NBF; t += 256)
        if (h[t]) atomicAdd(&bcnt[t], h[t]);
}

// ---------------- serial scan of bucket counts -> boff/gcur; also g[NR]=TOT ----------------
__global__ void scan_buckets_kernel(const int* __restrict__ bcnt, int nbu, int tot,
                                    int* __restrict__ boff, int* __restrict__ gcur,
                                    int* __restrict__ g, int NR)
{
    if (threadIdx.x == 0) {
        int acc = 0;
        for (int t = 0; t < nbu; ++t) { boff[t] = acc; gcur[t] = acc; acc += bcnt[t]; }
        boff[nbu] = acc;
        g[NR] = tot;
    }
}

// ---- Pass A: chunked bucket staging (runs reserved from gcur, regions = [boff[fb],boff[fb+1])) ----
__global__ __launch_bounds__(256)
void bucket_stage_kernel(const int* __restrict__ r0, const int* __restrict__ c0, const float* __restrict__ v0,
                         const int* __restrict__ r1, const int* __restrict__ c1, const float* __restrict__ v1,
                         const int* __restrict__ rD, const int* __restrict__ cD, const float* __restrict__ vD,
                         int E, int ED, int N,
                         int* __restrict__ gcur, ull_t* __restrict__ stg)
{
    __shared__ int hcnt[NBF];
    __shared__ int hbase[NBF];
    const int tid = threadIdx.x;
    for (int t = tid; t < NBF; t += 256) hcnt[t] = 0;
    __syncthreads();
    const long long tot = 2LL * E + ED;
    const long long base = (long long)blockIdx.x * EPB;
    #pragma unroll
    for (int k = 0; k < EPB / 256; ++k) {
        const long long i = base + k * 256 + tid;
        if (i < tot) {
            int vr;
            if (i < E)            vr = r0[i];
            else if (i < 2LL * E) vr = N + r1[i - E];
            else                  vr = 2 * N + rD[i - 2LL * E];
            atomicAdd(&hcnt[vr >> FBSH], 1);
        }
    }
    __syncthreads();
    for (int t = tid; t < NBF; t += 256) {
        const int c = hcnt[t];
        hbase[t] = c ? atomicAdd(&gcur[t], c) : 0;
        hcnt[t] = 0;  // reuse as local cursor
    }
    __syncthreads();
    #pragma unroll
    for (int k = 0; k < EPB / 256; ++k) {
        const long long i = base + k * 256 + tid;
        if (i < tot) {
            int vr, cc; float vv;
            if (i < E)            { vr = r0[i];                 cc = c0[i];            vv = v0[i]; }
            else if (i < 2LL * E) { vr = N + r1[i - E];         cc = c1[i - E];        vv = v1[i - E]; }
            else                  { vr = 2 * N + rD[i - 2LL * E]; cc = cD[i - 2LL * E]; vv = vD[i - 2LL * E]; }
            const int fb = vr >> FBSH;
            const int p = hbase[fb] + atomicAdd(&hcnt[fb], 1);
            stg[p] = ((ull_t)(unsigned)vr << 32) | ((unsigned)cc << 16) | f2bf(vv);
        }
    }
}

// ---- Pass B: per-bucket LDS row-hist + scan (writes g!) + counting sort -> coalesced ecv ----
__global__ __launch_bounds__(256)
void sort_bucket_kernel(const int* __restrict__ boff, int NR,
                        const ull_t* __restrict__ stg,
                        int* __restrict__ g, unsigned* __restrict__ ecv)
{
    __shared__ int hcnt[512];
    __shared__ int hscan[512];
    __shared__ unsigned pay[CAPB];
    const int b = blockIdx.x;
    const int r0 = b << FBSH;
    if (r0 >= NR) return;
    int r1 = r0 + (1 << FBSH); if (r1 > NR) r1 = NR;
    const int nrows = r1 - r0;
    const int base = boff[b], end = boff[b + 1];
    const int bsz = end - base;
    const int tid = threadIdx.x;
    hcnt[tid] = 0; hcnt[tid + 256] = 0;
    __syncthreads();
    // pass 1: per-row histogram
    for (int i = base + tid; i < end; i += 256)
        atomicAdd(&hcnt[(int)(stg[i] >> 32) - r0], 1);
    __syncthreads();
    // inclusive scan of 512 counters with 256 threads
    hscan[tid] = hcnt[tid]; hscan[tid + 256] = hcnt[tid + 256];
    __syncthreads();
    for (int o = 1; o < 512; o <<= 1) {
        const int a0 = (tid >= o) ? hscan[tid - o] : 0;
        const int a1 = (tid + 256 >= o) ? hscan[tid + 256 - o] : 0;
        __syncthreads();
        hscan[tid] += a0; hscan[tid + 256] += a1;
        __syncthreads();
    }
    // write global row pointers (exclusive) + convert hcnt to exclusive cursors
    if (tid < nrows)       g[r0 + tid]       = base + hscan[tid] - hcnt[tid];
    if (tid + 256 < nrows) g[r0 + tid + 256] = base + hscan[tid + 256] - hcnt[tid + 256];
    hcnt[tid]       = hscan[tid] - hcnt[tid];
    hcnt[tid + 256] = hscan[tid + 256] - hcnt[tid + 256];
    __syncthreads();
    if (bsz <= CAPB) {
        for (int i = base + tid; i < end; i += 256) {
            const ull_t t = stg[i];
            const int p = atomicAdd(&hcnt[(int)(t >> 32) - r0], 1);
            pay[p] = (unsigned)t;
        }
        __syncthreads();
        for (int i = tid; i < bsz; i += 256)
            ecv[base + i] = pay[i];
    } else {
        // overflow fallback: direct (single-block-local) scatter into ecv
        for (int i = base + tid; i < end; i += 256) {
            const ull_t t = stg[i];
            const int p = atomicAdd(&hcnt[(int)(t >> 32) - r0], 1);
            ecv[base + p] = (unsigned)t;
        }
    }
}

// ---------------- CSR SpMM, F=256: 1 row/wave, 2 edges/iter, 16B gathers ----------------
__global__ __launch_bounds__(256)
void spmm_f256(const int* __restrict__ rp, const unsigned* __restrict__ ecv,
               const ushort_t* __restrict__ X, ushort_t* __restrict__ Y,
               const float* __restrict__ bias, const float* __restrict__ ap, int n)
{
    const int r = blockIdx.x * 4 + (threadIdx.x >> 6);
    if (r >= n) return;
    const int lane = threadIdx.x & 63;
    const int half = lane >> 5;    // edge parity
    const int l    = lane & 31;    // 16B chunk (8 bf16 feats)
    const int s = rp[r], e = rp[r + 1];
    float acc[8] = {};
    #pragma unroll 2
    for (int j = s + half; j < e; j += 2) {
        const unsigned ev = ecv[j];
        const float v = bf2f((ushort_t)ev);
        const uint4 x = *reinterpret_cast<const uint4*>(X + (size_t)(ev >> 16) * H2C + l * 8);
        acc[0] += v * bf2f((ushort_t)x.x); acc[1] += v * bf2f((ushort_t)(x.x >> 16));
        acc[2] += v * bf2f((ushort_t)x.y); acc[3] += v * bf2f((ushort_t)(x.y >> 16));
        acc[4] += v * bf2f((ushort_t)x.z); acc[5] += v * bf2f((ushort_t)(x.z >> 16));
        acc[6] += v * bf2f((ushort_t)x.w); acc[7] += v * bf2f((ushort_t)(x.w >> 16));
    }
    #pragma unroll
    for (int k = 0; k < 8; ++k) acc[k] += __shfl_xor(acc[k], 32);
    if (half == 0) {
        const float a = ap[0];
        const int f0 = l * 8;
        const float4 b0v = *reinterpret_cast<const float4*>(bias + f0);
        const float4 b1v = *reinterpret_cast<const float4*>(bias + f0 + 4);
        const float bb[8] = {b0v.x, b0v.y, b0v.z, b0v.w, b1v.x, b1v.y, b1v.z, b1v.w};
        unsigned o[4];
        #pragma unroll
        for (int k = 0; k < 8; k += 2) {
            float tx = acc[k] + bb[k];
            float ty = acc[k + 1] + bb[k + 1];
            tx = tx >= 0.f ? tx : a * tx;  ty = ty >= 0.f ? ty : a * ty;
            tx = fmaxf(tx, 0.f);           ty = fmaxf(ty, 0.f);
            o[k >> 1] = ((unsigned)f2bf(ty) << 16) | f2bf(tx);
        }
        *reinterpret_cast<uint4*>(Y + (size_t)r * H2C + f0) = make_uint4(o[0], o[1], o[2], o[3]);
    }
}

// ---------------- CSR SpMM, F=128: 1 row/wave, 4 edges/iter, 16B gathers, fp32 out ----------------
__global__ __launch_bounds__(256)
void spmm_f128(const int* __restrict__ rp, const unsigned* __restrict__ ecv,
               const ushort_t* __restrict__ X, float* __restrict__ Y,
               const float* __restrict__ bias, const float* __restrict__ ap, int n)
{
    const int r = blockIdx.x * 4 + (threadIdx.x >> 6);
    if (r >= n) return;
    const int lane = threadIdx.x & 63;
    const int q = lane >> 4;   // edge in quad
    const int l = lane & 15;   // 16B chunk
    const int s = rp[r], e = rp[r + 1];
    float acc[8] = {};
    #pragma unroll 2
    for (int j = s + q; j < e; j += 4) {
        const unsigned ev = ecv[j];
        const float v = bf2f((ushort_t)ev);
        const uint4 x = *reinterpret_cast<const uint4*>(X + (size_t)(ev >> 16) * HDC + l * 8);
        acc[0] += v * bf2f((ushort_t)x.x); acc[1] += v * bf2f((ushort_t)(x.x >> 16));
        acc[2] += v * bf2f((ushort_t)x.y); acc[3] += v * bf2f((ushort_t)(x.y >> 16));
        acc[4] += v * bf2f((ushort_t)x.z); acc[5] += v * bf2f((ushort_t)(x.z >> 16));
        acc[6] += v * bf2f((ushort_t)x.w); acc[7] += v * bf2f((ushort_t)(x.w >> 16));
    }
    #pragma unroll
    for (int k = 0; k < 8; ++k) {
        acc[k] += __shfl_xor(acc[k], 16);
        acc[k] += __shfl_xor(acc[k], 32);
    }
    if (q == 0) {
        const float a = ap[0];
        const int f0 = l * 8;
        const float4 b0v = *reinterpret_cast<const float4*>(bias + f0);
        const float4 b1v = *reinterpret_cast<const float4*>(bias + f0 + 4);
        const float bb[8] = {b0v.x, b0v.y, b0v.z, b0v.w, b1v.x, b1v.y, b1v.z, b1v.w};
        float o[8];
        #pragma unroll
        for (int k = 0; k < 8; ++k) {
            float t = acc[k] + bb[k];
            o[k] = t >= 0.f ? t : a * t;
        }
        *reinterpret_cast<float4*>(Y + (size_t)r * HDC + f0)     = make_float4(o[0], o[1], o[2], o[3]);
        *reinterpret_cast<float4*>(Y + (size_t)r * HDC + f0 + 4) = make_float4(o[4], o[5], o[6], o[7]);
    }
}

// ---------------- gate precompute ----------------
__global__ void gate_pre_kernel(const float* __restrict__ G1w, const float* __restrict__ G1b,
                                const float* __restrict__ G2w, const float* __restrict__ G2b,
                                const float* __restrict__ G3w, const float* __restrict__ G3b,
                                float* __restrict__ U)
{
    const int h = threadIdx.x;  // 0..127
    float s1 = 0.f, s2 = 0.f;
    for (int g = 0; g < GATEC; ++g) {
        s1 += G1w[h * GATEC + g] * G3w[g];
        s2 += G2w[h * GATEC + g] * G3w[GATEC + g];
    }
    U[h] = s1;
    U[HDC + h] = s2;
    if (h == 0) {
        float c = G3b[0];
        for (int g = 0; g < GATEC; ++g)
            c += G1b[g] * G3w[g] + G2b[g] * G3w[GATEC + g];
        U[2 * HDC] = c;
        U[2 * HDC + 1] = G3w[2 * GATEC];
    }
}

// ---------------- beta ----------------
__global__ __launch_bounds__(256)
void beta_kernel(const float* __restrict__ h1, const float* __restrict__ h3,
                 const float* __restrict__ deg, const float* __restrict__ U,
                 float* __restrict__ beta, int n)
{
    const int i = blockIdx.x * blockDim.x + threadIdx.x;
    if (i >= n) return;
    const float c = U[2 * HDC], wd = U[2 * HDC + 1];
    float s = c + wd * deg[i];
    const float4* h1p = reinterpret_cast<const float4*>(h1 + (size_t)i * HDC);
    const float4* h3p = reinterpret_cast<const float4*>(h3 + (size_t)i * HDC);
    const float4* u1p = reinterpret_cast<const float4*>(U);
    const float4* u2p = reinterpret_cast<const float4*>(U + HDC);
    #pragma unroll 8
    for (int j = 0; j < HDC / 4; ++j) {
        const float4 a = h1p[j], b = u1p[j];
        s += a.x * b.x + a.y * b.y + a.z * b.z + a.w * b.w;
        const float4 a2 = h3p[j], b2 = u2p[j];
        s += a2.x * b2.x + a2.y * b2.y + a2.z * b2.z + a2.w * b2.w;
    }
    beta[i] = 1.f / (1.f + expf(-s));
}

extern "C" void kernel_launch(void* const* d_in, const int* in_sizes, int n_in,
                              void* d_out, int out_size, void* d_ws, size_t ws_size,
                              hipStream_t stream)
{
    const float* x1  = (const float*)d_in[0];
    const float* x2  = (const float*)d_in[1];
    const int*   a1r = (const int*)d_in[2];
    const int*   a1c = (const int*)d_in[3];
    const float* a1v = (const float*)d_in[4];
    const int*   a2r = (const int*)d_in[5];
    const int*   a2c = (const int*)d_in[6];
    const float* a2v = (const float*)d_in[7];
    const int*   dr  = (const int*)d_in[8];
    const int*   dc  = (const int*)d_in[9];
    const float* dv  = (const float*)d_in[10];
    const float* deg = (const float*)d_in[11];
    const float* W0  = (const float*)d_in[12];
    const float* b0  = (const float*)d_in[13];
    const float* a0  = (const float*)d_in[14];
    const float* W1  = (const float*)d_in[15];
    const float* b1  = (const float*)d_in[16];
    const float* a1p = (const float*)d_in[17];
    const float* G1w = (const float*)d_in[18];
    const float* G1b = (const float*)d_in[19];
    const float* G2w = (const float*)d_in[20];
    const float* G2b = (const float*)d_in[21];
    const float* G3w = (const float*)d_in[22];
    const float* G3b = (const float*)d_in[23];

    const int E  = in_sizes[2];
    const int ED = in_sizes[8];
    const int N  = in_sizes[11];
    const int IN = in_sizes[0] / N;   // 256
    const long long TOT = 2LL * E + ED;
    const int NR  = 3 * N;
    const int NBUSED = (NR + (1 << FBSH) - 1) >> FBSH;   // 293

    // ---- workspace bump allocator (256 B aligned) ----
    char* base = (char*)d_ws;
    size_t off = 0;
    auto alloc = [&](size_t bytes) -> char* {
        char* p = base + off;
        off += (bytes + 255) & ~(size_t)255;
        return p;
    };
    // XW12b: row-major bf16 [2N][256] = [x1@W0 ; x2@W0]
    ushort_t* XW12b = (ushort_t*)alloc((size_t)2 * N * H2C * 2);
    // Region R: stg (TOT*8 B) -> Xb12 (2N*256 bf16) -> Bbb (N*256 bf16) + Cbb (N*128 bf16)
    char* R = alloc((size_t)2 * N * H2C * 2);
    ull_t*    stg  = (ull_t*)R;
    ushort_t* Xb12 = (ushort_t*)R;
    ushort_t* Bbb  = (ushort_t*)R;
    ushort_t* Cbb  = (ushort_t*)(R + (size_t)N * H2C * 2);
    ushort_t* W0T  = (ushort_t*)alloc((size_t)H2C * H2C * 2);
    ushort_t* W1T  = (ushort_t*)alloc((size_t)HDC * H2C * 2);
    float*    U    = (float*)alloc(258 * 4);
    int*  g       = (int*)alloc((size_t)(NR + 1) * 4);
    int*  bcnt    = (int*)alloc(NBF * 4);
    int*  boff    = (int*)alloc((NBF + 1) * 4);
    int*  gcur    = (int*)alloc(NBF * 4);
    unsigned* ecv = (unsigned*)alloc((size_t)TOT * 4);

    float* out  = (float*)d_out;
    float* h1   = out;
    float* h2   = out + 1 * (size_t)N * HDC;
    float* h3   = out + 2 * (size_t)N * HDC;
    float* h4   = out + 3 * (size_t)N * HDC;
    float* beta = out + 4 * (size_t)N * HDC;

    // ---- small precomputes ----
    gate_pre_kernel<<<1, HDC, 0, stream>>>(G1w, G1b, G2w, G2b, G3w, G3b, U);
    transpose_f2bf_kernel<<<dim3((H2C * H2C + 255) / 256), 256, 0, stream>>>(W0, W0T, H2C, H2C);
    transpose_f2bf_kernel<<<dim3((H2C * HDC + 255) / 256), 256, 0, stream>>>(W1, W1T, H2C, HDC);

    // ---- bucket-level histogram + scan ----
    hipMemsetAsync(bcnt, 0, NBF * 4, stream);
    bucket_hist_kernel<<<dim3((unsigned)((TOT + EPBH - 1) / EPBH)), 256, 0, stream>>>(
        a1r, a2r, dr, E, ED, N, bcnt);
    scan_buckets_kernel<<<1, 64, 0, stream>>>(bcnt, NBUSED, (int)TOT, boff, gcur, g, NR);

    // ---- two-pass sort: chunked bucket stage -> LDS row-hist+scan (writes g) + counting sort ----
    bucket_stage_kernel<<<dim3((unsigned)((TOT + EPB - 1) / EPB)), 256, 0, stream>>>(
        a1r, a1c, a1v, a2r, a2c, a2v, dr, dc, dv, E, ED, N, gcur, stg);
    sort_bucket_kernel<<<dim3(NBUSED), 256, 0, stream>>>(boff, NR, stg, g, ecv);

    const int* rp1 = g;
    const int* rp2 = g + N;
    const int* rpD = g + 2 * N;

    // ---- x -> bf16 (both inputs), batched XW GEMM (2N rows) ----
    f2bf_pair_kernel<<<dim3(2048), 256, 0, stream>>>(x1, x2, Xb12, (long long)N * H2C / 4);
    gemm_bf16_mfma<<<dim3(H2C / 128, (2 * N + 127) / 128), 256, 0, stream>>>(
        Xb12, W0T, XW12b, 2 * N, H2C, IN);

    auto run_branch = [&](const int* rp, const ushort_t* Xsrc, float* hout) {
        spmm_f256<<<dim3((N + 3) / 4), 256, 0, stream>>>(rp, ecv, Xsrc, Bbb, b0, a0, N);
        gemm_bf16_mfma<<<dim3(HDC / 128, (N + 127) / 128), 256, 0, stream>>>(
            Bbb, W1T, Cbb, N, HDC, H2C);
        spmm_f128<<<dim3((N + 3) / 4), 256, 0, stream>>>(rp, ecv, Cbb, hout, b1, a1p, N);
    };

    const ushort_t* XW1b = XW12b;
    const ushort_t* XW2b = XW12b + (size_t)N * H2C;

    run_branch(rp1, XW1b, h1);
    run_branch(rp2, XW1b, h3);
    run_branch(rpD, XW1b, h4);
    run_branch(rp1, XW2b, h2);

    beta_kernel<<<dim3((N + 255) / 256), 256, 0, stream>>>(h1, h3, deg, U, beta, N);
}